// Round 1
// baseline (17547.916 us; speedup 1.0000x reference)
//
#include <hip/hip_runtime.h>
#include <math.h>

#define NSTEPS 512
#define BATCH  256
#define NIN    64
#define NN     256   // neurons

// ---------------------------------------------------------------------------
// Phase 1: fused input projection + recurrent tanh RNN.
// grid = BATCH blocks (one batch row), 512 threads: t -> (n = t>>1, half = t&1).
// W_ih/W_hh half-rows live in VGPRs; h lives in LDS (broadcast reads).
// Writes out_pre (S,B,N) fp32 to workspace.
// ---------------------------------------------------------------------------
extern "C" __global__ void __launch_bounds__(512, 2)
rnn_kernel(const float* __restrict__ X, const float* __restrict__ W_ih,
           const float* __restrict__ W_hh, const float* __restrict__ b_ih,
           const float* __restrict__ b_hh, float* __restrict__ A)
{
    const int b    = blockIdx.x;
    const int t    = threadIdx.x;
    const int n    = t >> 1;
    const int half = t & 1;

    __shared__ float h_lds[NN];
    __shared__ float x_lds[NIN];

    float wih[NIN / 2];
#pragma unroll
    for (int j = 0; j < NIN / 2; ++j) wih[j] = W_ih[n * NIN + half * (NIN / 2) + j];
    float whh[NN / 2];
#pragma unroll
    for (int j = 0; j < NN / 2; ++j) whh[j] = W_hh[n * NN + half * (NN / 2) + j];
    const float bias = b_ih[n] + b_hh[n];

    if (t < NN) h_lds[t] = 0.0f;
    __syncthreads();

    for (int s = 0; s < NSTEPS; ++s) {
        if (t < NIN) x_lds[t] = X[(s * BATCH + b) * NIN + t];
        __syncthreads();

        float acc0 = 0.f, acc1 = 0.f, acc2 = 0.f, acc3 = 0.f;
#pragma unroll
        for (int j = 0; j < NIN / 2; j += 4) {
            const float* xp = &x_lds[half * (NIN / 2) + j];
            acc0 = fmaf(wih[j + 0], xp[0], acc0);
            acc1 = fmaf(wih[j + 1], xp[1], acc1);
            acc2 = fmaf(wih[j + 2], xp[2], acc2);
            acc3 = fmaf(wih[j + 3], xp[3], acc3);
        }
#pragma unroll
        for (int j = 0; j < NN / 2; j += 4) {
            const float* hp = &h_lds[half * (NN / 2) + j];
            acc0 = fmaf(whh[j + 0], hp[0], acc0);
            acc1 = fmaf(whh[j + 1], hp[1], acc1);
            acc2 = fmaf(whh[j + 2], hp[2], acc2);
            acc3 = fmaf(whh[j + 3], hp[3], acc3);
        }
        float acc = (acc0 + acc1) + (acc2 + acc3);
        acc += __shfl_xor(acc, 1);           // combine the two k-halves
        const float hn = tanhf(acc + bias);

        __syncthreads();                      // everyone done reading h_lds/x_lds
        h_lds[n] = hn;                        // both halves write same value (benign)
        if (half == 0) A[(size_t)(s * BATCH + b) * NN + n] = hn;
    }
}

// ---------------------------------------------------------------------------
// Phase 2: 256-iteration attention loop + final FC, one block per batch row.
// Flash-style single pass over A per iteration (online softmax), chunks of
// CH=128 time rows staged in LDS with quarter-padded layout (stride 260,
// quarters at q*65) -> every LDS access pattern is <=2-way (free).
// ---------------------------------------------------------------------------
#define CH 128
#define A_STRIDE 260          // words per staged row: 4 quarters of 65
#define A_WORDS  (CH * A_STRIDE)            // 33280
#define LDS_FLOATS (A_WORDS + NN + NN + 2 * NN + CH + CH + 8)
#define LDS_BYTES  (LDS_FLOATS * 4)         // 138272

extern "C" __global__ void __launch_bounds__(512, 2)
attn_kernel(const float* __restrict__ A, const float* __restrict__ Wc_ih,
            const float* __restrict__ Wc_hh, const float* __restrict__ bc_ih,
            const float* __restrict__ bc_hh, const float* __restrict__ W_fc,
            const float* __restrict__ b_fc, float* __restrict__ out)
{
    extern __shared__ float sm[];
    float* a_lds   = sm;                      // CH x A_STRIDE
    float* hp_lds  = sm + A_WORDS;            // NN
    float* att_lds = hp_lds + NN;             // NN
    float* attp    = att_lds + NN;            // 2*NN
    float* pre_lds = attp + 2 * NN;           // CH
    float* e_lds   = pre_lds + CH;            // CH
    float* red     = e_lds + CH;              // 8 scratch scalars

    const int b    = blockIdx.x;
    const int t    = threadIdx.x;
    const int lane = t & 63;
    const int wid  = t >> 6;

    const int r_dot = t >> 2, q_dot = t & 3;          // dot phase: 128 rows x 4 quarters
    const int n_att = t & 255, sh_att = t >> 8;       // att phase: 256 cols x 2 row-halves
    const int w_n   = ((n_att >> 6) * 65) + (n_att & 63);
    const int nw    = t >> 1, kh = t & 1;             // hp-update: 256 n x 2 k-halves
    const int st_col  = t & 255;                      // staging
    const int st_th   = t >> 8;
    const int st_wcol = ((st_col >> 6) * 65) + (st_col & 63);
    const float bcs = bc_ih[nw] + bc_hh[nw];

    if (t < NN) hp_lds[t] = 0.0f;
    __syncthreads();

    const float* Ab = A + (size_t)b * NN;   // A[(s*BATCH+b)*NN + col]

    for (int it = 0; it < NN; ++it) {
        // hp quarter into regs (reused across all 4 chunks)
        float hpr[64];
#pragma unroll
        for (int j = 0; j < 64; ++j) hpr[j] = hp_lds[q_dot * 64 + j];

        float m = -INFINITY, l = 0.f, attacc = 0.f;

        for (int c = 0; c < NSTEPS / CH; ++c) {
            // ---- stage CH rows (coalesced global, 64 loads/thread)
#pragma unroll 8
            for (int i = 0; i < 64; ++i) {
                const int row = 2 * i + st_th;
                const int s   = c * CH + row;
                a_lds[row * A_STRIDE + st_wcol] = Ab[(size_t)s * (BATCH * NN) + st_col];
            }
            __syncthreads();

            // ---- pre[r] = <A_row r, hp>, r in [0,CH)
            {
                float p0 = 0, p1 = 0, p2 = 0, p3 = 0;
                const float* arow = &a_lds[r_dot * A_STRIDE + q_dot * 65];
#pragma unroll
                for (int j = 0; j < 64; j += 4) {
                    p0 = fmaf(arow[j + 0], hpr[j + 0], p0);
                    p1 = fmaf(arow[j + 1], hpr[j + 1], p1);
                    p2 = fmaf(arow[j + 2], hpr[j + 2], p2);
                    p3 = fmaf(arow[j + 3], hpr[j + 3], p3);
                }
                float p = (p0 + p1) + (p2 + p3);
                p += __shfl_xor(p, 1);
                p += __shfl_xor(p, 2);
                if (q_dot == 0) pre_lds[r_dot] = p;
            }
            __syncthreads();

            // ---- chunk max (waves 0,1 cover the 128 pre values)
            if (t < CH) {
                float v = pre_lds[t];
#pragma unroll
                for (int o = 32; o > 0; o >>= 1) v = fmaxf(v, __shfl_xor(v, o));
                if (lane == 0) red[wid] = v;
            }
            __syncthreads();
            const float cmax = fmaxf(red[0], red[1]);
            const float newm = fmaxf(m, cmax);
            const float rs   = expf(m - newm);   // m=-inf -> 0 on first chunk
            attacc *= rs;
            if (t < CH) {
                const float e = expf(pre_lds[t] - newm);
                e_lds[t] = e;
                float sv = e;
#pragma unroll
                for (int o = 32; o > 0; o >>= 1) sv += __shfl_xor(sv, o);
                if (lane == 0) red[4 + wid] = sv;
            }
            __syncthreads();
            l = l * rs + red[4] + red[5];
            m = newm;

            // ---- att accumulate: attacc[n] += sum_r e_r * A[r][n]
            {
                const float* acol = &a_lds[w_n];
#pragma unroll 16
                for (int i = 0; i < 64; ++i) {
                    const int row = sh_att * 64 + i;
                    attacc = fmaf(e_lds[row], acol[row * A_STRIDE], attacc);
                }
            }
            __syncthreads();   // a_lds/pre/e reused next chunk
        }

        // combine the two s-halves and normalize
        attp[sh_att * 256 + n_att] = attacc;
        __syncthreads();
        if (t < NN) att_lds[t] = (attp[t] + attp[256 + t]) / l;
        __syncthreads();

        // ---- hp_new = tanh(Wc_ih hp + bc_ih + Wc_hh att + bc_hh)
        {
            float acc0 = 0.f, acc1 = 0.f;
            const float* wih_row = &Wc_ih[nw * NN + kh * 128];
            const float* whh_row = &Wc_hh[nw * NN + kh * 128];
            const float* hpp = &hp_lds[kh * 128];
            const float* atp = &att_lds[kh * 128];
#pragma unroll 16
            for (int k = 0; k < 128; ++k) {
                acc0 = fmaf(wih_row[k], hpp[k], acc0);
                acc1 = fmaf(whh_row[k], atp[k], acc1);
            }
            float acc = acc0 + acc1;
            acc += __shfl_xor(acc, 1);
            const float hn = tanhf(acc + bcs);
            __syncthreads();                 // everyone done reading hp_lds
            hp_lds[nw] = hn;                 // both k-halves write same value
        }
        __syncthreads();
    }

    // ---- final FC: out[b] = <hidden, W_fc> + b_fc
    float v = (t < NN) ? hp_lds[t] * W_fc[t] : 0.f;
#pragma unroll
    for (int o = 32; o > 0; o >>= 1) v += __shfl_xor(v, o);
    if (lane == 0) red[wid] = v;
    __syncthreads();
    if (t == 0) out[b] = red[0] + red[1] + red[2] + red[3] + b_fc[0];
}

// ---------------------------------------------------------------------------
extern "C" void kernel_launch(void* const* d_in, const int* in_sizes, int n_in,
                              void* d_out, int out_size, void* d_ws, size_t ws_size,
                              hipStream_t stream) {
    const float* X     = (const float*)d_in[0];
    const float* W_ih  = (const float*)d_in[1];
    const float* W_hh  = (const float*)d_in[2];
    const float* b_ih  = (const float*)d_in[3];
    const float* b_hh  = (const float*)d_in[4];
    const float* Wc_ih = (const float*)d_in[5];
    const float* Wc_hh = (const float*)d_in[6];
    const float* bc_ih = (const float*)d_in[7];
    const float* bc_hh = (const float*)d_in[8];
    const float* W_fc  = (const float*)d_in[9];
    const float* b_fc  = (const float*)d_in[10];
    float* out = (float*)d_out;
    float* A   = (float*)d_ws;   // out_pre: 512*256*256 fp32 = 128 MiB

    hipFuncSetAttribute((const void*)attn_kernel,
                        hipFuncAttributeMaxDynamicSharedMemorySize, LDS_BYTES);

    rnn_kernel<<<BATCH, 512, 0, stream>>>(X, W_ih, W_hh, b_ih, b_hh, A);
    attn_kernel<<<BATCH, 512, LDS_BYTES, stream>>>(A, Wc_ih, Wc_hh, bc_ih, bc_hh,
                                                   W_fc, b_fc, out);
}

// Round 3
// 17263.638 us; speedup vs baseline: 1.0165x; 1.0165x over previous
//
#include <hip/hip_runtime.h>
#include <hip/hip_fp16.h>
#include <math.h>

#define NSTEPS 512
#define BATCH  256
#define NIN    64
#define NN     256

// ===========================================================================
// Phase 0: pack Wc_ih / Wc_hh into transposed, k-quad-packed fp16:
//   W4T[(m*64 + kq)*256 + n] = half4{ Wc_m[n][4kq .. 4kq+3] }  (as uint2)
// so the attn hp-update reads are lane-coalesced 8B loads.
// ===========================================================================
extern "C" __global__ void pack_kernel(const float* __restrict__ Wc_ih,
                                       const float* __restrict__ Wc_hh,
                                       uint2* __restrict__ W4T)
{
    const int n = blockIdx.x;      // 0..255 output row
    const int t = threadIdx.x;     // 0..63  k-quad
    {
        float4 v = ((const float4*)(Wc_ih + n * NN))[t];
        __half2 a = __floats2half2_rn(v.x, v.y);
        __half2 c = __floats2half2_rn(v.z, v.w);
        uint2 o; o.x = *(uint32_t*)&a; o.y = *(uint32_t*)&c;
        W4T[t * 256 + n] = o;
    }
    {
        float4 v = ((const float4*)(Wc_hh + n * NN))[t];
        __half2 a = __floats2half2_rn(v.x, v.y);
        __half2 c = __floats2half2_rn(v.z, v.w);
        uint2 o; o.x = *(uint32_t*)&a; o.y = *(uint32_t*)&c;
        W4T[(64 + t) * 256 + n] = o;
    }
}

// ===========================================================================
// Phase 1: tanh RNN. One block per batch row, 512 threads: (n = t>>1, half).
// Writes A2 in (B, S, N) layout as fp16 (packed half2 stores via shuffle).
// ===========================================================================
extern "C" __global__ void __launch_bounds__(512, 2)
rnn_kernel(const float* __restrict__ X, const float* __restrict__ W_ih,
           const float* __restrict__ W_hh, const float* __restrict__ b_ih,
           const float* __restrict__ b_hh, __half* __restrict__ A2)
{
    const int b    = blockIdx.x;
    const int t    = threadIdx.x;
    const int n    = t >> 1;
    const int half = t & 1;

    __shared__ float h_lds[NN];
    __shared__ float x_lds[NIN];

    float wih[NIN / 2];
#pragma unroll
    for (int j = 0; j < NIN / 2; ++j) wih[j] = W_ih[n * NIN + half * (NIN / 2) + j];
    float whh[NN / 2];
#pragma unroll
    for (int j = 0; j < NN / 2; ++j) whh[j] = W_hh[n * NN + half * (NN / 2) + j];
    const float bias = b_ih[n] + b_hh[n];

    if (t < NN) h_lds[t] = 0.0f;
    __syncthreads();

    __half2* Ab2 = (__half2*)(A2 + (size_t)b * NSTEPS * NN);

    for (int s = 0; s < NSTEPS; ++s) {
        if (t < NIN) x_lds[t] = X[(s * BATCH + b) * NIN + t];
        __syncthreads();

        float acc0 = 0.f, acc1 = 0.f, acc2 = 0.f, acc3 = 0.f;
#pragma unroll
        for (int j = 0; j < NIN / 2; j += 4) {
            const float* xp = &x_lds[half * (NIN / 2) + j];
            acc0 = fmaf(wih[j + 0], xp[0], acc0);
            acc1 = fmaf(wih[j + 1], xp[1], acc1);
            acc2 = fmaf(wih[j + 2], xp[2], acc2);
            acc3 = fmaf(wih[j + 3], xp[3], acc3);
        }
#pragma unroll
        for (int j = 0; j < NN / 2; j += 4) {
            const float* hp = &h_lds[half * (NN / 2) + j];
            acc0 = fmaf(whh[j + 0], hp[0], acc0);
            acc1 = fmaf(whh[j + 1], hp[1], acc1);
            acc2 = fmaf(whh[j + 2], hp[2], acc2);
            acc3 = fmaf(whh[j + 3], hp[3], acc3);
        }
        float acc = (acc0 + acc1) + (acc2 + acc3);
        acc += __shfl_xor(acc, 1);
        const float hn = tanhf(acc + bias);

        __syncthreads();
        h_lds[n] = hn;
        const float hn_nb = __shfl_down(hn, 2);     // neighbor n+1's value
        if ((t & 3) == 0)
            Ab2[s * (NN / 2) + (t >> 2)] = __floats2half2_rn(hn, hn_nb);
    }
}

// ===========================================================================
// Phase 2: 256-iteration attention loop. One block per batch, 512 threads.
// A_b streamed in 4 chunks of 128 rows (fp16), double-buffered LDS with
// register prefetch; 16B-granular XOR swizzle phys_w = w ^ ((row&7)<<2).
// fp32 accumulation everywhere; Wc fp16 quad-packed from L2.
// ===========================================================================
#define CH      128
#define AWORDS  (CH * 128)                 // words (half2) per chunk buffer
#define HP_PAD  68                         // 64 data + 4 pad per quarter
#define LDS_WORDS (2 * AWORDS)             // 32768 words = 128 KiB
#define LDS_EXTRA (HP_PAD*4 + HP_PAD*4 + 8*256 + 128 + 128 + 8)
#define LDS_BYTES (LDS_WORDS * 4 + LDS_EXTRA * 4)

extern "C" __global__ void __launch_bounds__(512, 2)
attn_kernel(const __half* __restrict__ A2, const uint2* __restrict__ W4T,
            const float* __restrict__ bc_ih, const float* __restrict__ bc_hh,
            const float* __restrict__ W_fc, const float* __restrict__ b_fc,
            float* __restrict__ out)
{
    extern __shared__ float sm[];
    uint32_t* aw     = (uint32_t*)sm;                    // 2 chunk buffers
    float*    hp_lds = sm + LDS_WORDS;                   // 4*68 padded
    float*    att_lds= hp_lds + HP_PAD * 4;              // 4*68 padded
    float*    attp   = att_lds + HP_PAD * 4;             // 8*256 partials
    float*    pre_lds= attp + 8 * 256;                   // 128
    float*    e_lds  = pre_lds + 128;                    // 128
    float*    red    = e_lds + 128;                      // 8

    const int b    = blockIdx.x;
    const int t    = threadIdx.x;
    const int lane = t & 63;
    const int wid  = t >> 6;

    const int pr = t >> 2, pq = t & 3, psw = (pr & 7) << 2;   // pre-dot
    const int ac4 = t & 63, ash = t >> 6;                     // att accum
    const int srow = t >> 5, sa = t & 31;                     // staging
    const int um = t >> 8, un = t & 255;                      // hp-update
    const float bcs = (t < 256) ? (bc_ih[un] + bc_hh[un]) : 0.f;

    if (t < 256) hp_lds[(t >> 6) * HP_PAD + (t & 63)] = 0.f;

    const uint4* gA = (const uint4*)(A2 + (size_t)b * NSTEPS * NN);

    // prologue: stage chunk 0 into buffer 0
    {
        uint4 ld[8];
#pragma unroll
        for (int i = 0; i < 8; ++i) {
            const int row = i * 16 + srow;
            ld[i] = gA[(row << 5) + sa];
        }
#pragma unroll
        for (int i = 0; i < 8; ++i) {
            const int row = i * 16 + srow;
            *(uint4*)&aw[row * 128 + ((4 * sa) ^ ((row & 7) << 2))] = ld[i];
        }
    }
    __syncthreads();

    for (int it = 0; it < NN; ++it) {
        // hp quarter (columns pq*64..+63) into registers
        float hpr[64];
        {
            const float4* hq = (const float4*)(hp_lds + pq * HP_PAD);
#pragma unroll
            for (int j = 0; j < 16; ++j) {
                float4 v = hq[j];
                hpr[4 * j + 0] = v.x; hpr[4 * j + 1] = v.y;
                hpr[4 * j + 2] = v.z; hpr[4 * j + 3] = v.w;
            }
        }

        float m = -INFINITY, l = 0.f;
        float att4[4] = {0.f, 0.f, 0.f, 0.f};

        for (int c = 0; c < 4; ++c) {
            const int bb = c & 1;
            const int nc = (c + 1) & 3;     // next chunk (wraps for next iter)

            // T14: issue next-chunk global loads now, write to LDS after att
            uint4 ld[8];
#pragma unroll
            for (int i = 0; i < 8; ++i) {
                const int row = i * 16 + srow;
                ld[i] = gA[((nc * CH + row) << 5) + sa];
            }

            // ---- pre[r] = <A_row r, hp>
            {
                float acc = 0.f;
                const uint32_t* ab = aw + bb * AWORDS + pr * 128 + pq * 32;
#pragma unroll
                for (int jj = 0; jj < 8; ++jj) {
                    uint4 w = *(const uint4*)&ab[(4 * jj) ^ psw];
                    float2 f0 = __half22float2(*(__half2*)&w.x);
                    float2 f1 = __half22float2(*(__half2*)&w.y);
                    float2 f2 = __half22float2(*(__half2*)&w.z);
                    float2 f3 = __half22float2(*(__half2*)&w.w);
                    acc = fmaf(f0.x, hpr[8 * jj + 0], acc);
                    acc = fmaf(f0.y, hpr[8 * jj + 1], acc);
                    acc = fmaf(f1.x, hpr[8 * jj + 2], acc);
                    acc = fmaf(f1.y, hpr[8 * jj + 3], acc);
                    acc = fmaf(f2.x, hpr[8 * jj + 4], acc);
                    acc = fmaf(f2.y, hpr[8 * jj + 5], acc);
                    acc = fmaf(f3.x, hpr[8 * jj + 6], acc);
                    acc = fmaf(f3.y, hpr[8 * jj + 7], acc);
                }
                acc += __shfl_xor(acc, 1);
                acc += __shfl_xor(acc, 2);
                if (pq == 0) pre_lds[pr] = acc;
            }
            __syncthreads();

            // ---- online softmax (chunk max, then e + sum)
            if (t < CH) {
                float v = pre_lds[t];
#pragma unroll
                for (int o = 32; o > 0; o >>= 1) v = fmaxf(v, __shfl_xor(v, o));
                if (lane == 0) red[wid] = v;
            }
            __syncthreads();
            const float cmax = fmaxf(red[0], red[1]);
            const float newm = fmaxf(m, cmax);
            const float rs   = expf(m - newm);     // 0 on first chunk
            if (t < CH) {
                const float e = expf(pre_lds[t] - newm);
                e_lds[t] = e;
                float sv = e;
#pragma unroll
                for (int o = 32; o > 0; o >>= 1) sv += __shfl_xor(sv, o);
                if (lane == 0) red[4 + wid] = sv;
            }
            __syncthreads();
            l = l * rs + red[4] + red[5];
            m = newm;
#pragma unroll
            for (int j = 0; j < 4; ++j) att4[j] *= rs;

            // ---- att accumulate: cols 4*ac4..+3, rows ash*16..+15
            {
                const uint32_t* ac = aw + bb * AWORDS;
#pragma unroll
                for (int i = 0; i < 16; ++i) {
                    const int row = ash * 16 + i;
                    const float e = e_lds[row];
                    uint2 wv = *(const uint2*)&ac[row * 128 + ((2 * ac4) ^ ((row & 7) << 2))];
                    float2 f0 = __half22float2(*(__half2*)&wv.x);
                    float2 f1 = __half22float2(*(__half2*)&wv.y);
                    att4[0] = fmaf(e, f0.x, att4[0]);
                    att4[1] = fmaf(e, f0.y, att4[1]);
                    att4[2] = fmaf(e, f1.x, att4[2]);
                    att4[3] = fmaf(e, f1.y, att4[3]);
                }
            }

            // ---- write prefetched next chunk into other buffer
#pragma unroll
            for (int i = 0; i < 8; ++i) {
                const int row = i * 16 + srow;
                *(uint4*)&aw[(1 - bb) * AWORDS + row * 128 +
                             ((4 * sa) ^ ((row & 7) << 2))] = ld[i];
            }
            __syncthreads();
        }

        // ---- combine att partials, normalize
        *(float4*)&attp[ash * 256 + ac4 * 4] =
            make_float4(att4[0], att4[1], att4[2], att4[3]);
        __syncthreads();
        if (t < 256) {
            float s = 0.f;
#pragma unroll
            for (int sh = 0; sh < 8; ++sh) s += attp[sh * 256 + t];
            att_lds[(t >> 6) * HP_PAD + (t & 63)] = s / l;
        }
        __syncthreads();

        // ---- hp_new = tanh(Wc_ih hp + Wc_hh att + bc); split: um=0 -> ih
        {
            const uint2* Wp = W4T + (um << 14) + un;
            const float4* v4 = (const float4*)(um ? att_lds : hp_lds);
            float acc = 0.f;
#pragma unroll
            for (int q = 0; q < 4; ++q) {
#pragma unroll
                for (int j2 = 0; j2 < 16; ++j2) {
                    float4 v = v4[q * 17 + j2];
                    uint2 ww = Wp[(q * 16 + j2) << 8];
                    float2 f0 = __half22float2(*(__half2*)&ww.x);
                    float2 f1 = __half22float2(*(__half2*)&ww.y);
                    acc = fmaf(f0.x, v.x, acc);
                    acc = fmaf(f0.y, v.y, acc);
                    acc = fmaf(f1.x, v.z, acc);
                    acc = fmaf(f1.y, v.w, acc);
                }
            }
            attp[um * 256 + un] = acc;   // attp reuse (partials already consumed)
        }
        __syncthreads();
        if (t < 256) {
            const float hn = tanhf(attp[t] + attp[256 + t] + bcs);
            hp_lds[(t >> 6) * HP_PAD + (t & 63)] = hn;
        }
        __syncthreads();
    }

    // ---- final FC
    float v = (t < 256) ? hp_lds[(t >> 6) * HP_PAD + (t & 63)] * W_fc[un] : 0.f;
#pragma unroll
    for (int o = 32; o > 0; o >>= 1) v += __shfl_xor(v, o);
    if (lane == 0) red[wid] = v;
    __syncthreads();
    if (t == 0) {
        float s = b_fc[0];
#pragma unroll
        for (int w = 0; w < 8; ++w) s += red[w];
        out[b] = s;
    }
}

// ===========================================================================
extern "C" void kernel_launch(void* const* d_in, const int* in_sizes, int n_in,
                              void* d_out, int out_size, void* d_ws, size_t ws_size,
                              hipStream_t stream) {
    const float* X     = (const float*)d_in[0];
    const float* W_ih  = (const float*)d_in[1];
    const float* W_hh  = (const float*)d_in[2];
    const float* b_ih  = (const float*)d_in[3];
    const float* b_hh  = (const float*)d_in[4];
    const float* Wc_ih = (const float*)d_in[5];
    const float* Wc_hh = (const float*)d_in[6];
    const float* bc_ih = (const float*)d_in[7];
    const float* bc_hh = (const float*)d_in[8];
    const float* W_fc  = (const float*)d_in[9];
    const float* b_fc  = (const float*)d_in[10];
    float* out = (float*)d_out;

    __half* A2  = (__half*)d_ws;                                   // 64 MiB
    uint2*  W4T = (uint2*)((char*)d_ws + (size_t)64 * 1024 * 1024); // 256 KiB

    hipFuncSetAttribute((const void*)attn_kernel,
                        hipFuncAttributeMaxDynamicSharedMemorySize, LDS_BYTES);

    pack_kernel<<<256, 64, 0, stream>>>(Wc_ih, Wc_hh, W4T);
    rnn_kernel<<<BATCH, 512, 0, stream>>>(X, W_ih, W_hh, b_ih, b_hh, A2);
    attn_kernel<<<BATCH, 512, LDS_BYTES, stream>>>(A2, W4T, bc_ih, bc_hh,
                                                   W_fc, b_fc, out);
}

// Round 4
// 9530.877 us; speedup vs baseline: 1.8412x; 1.8113x over previous
//
#include <hip/hip_runtime.h>
#include <hip/hip_fp16.h>
#include <math.h>

#define NSTEPS 512
#define BATCH  256
#define NIN    64
#define NN     256

__device__ __forceinline__ void gll16(const void* gp, void* lp) {
    __builtin_amdgcn_global_load_lds(
        (const __attribute__((address_space(1))) void*)gp,
        (__attribute__((address_space(3))) void*)lp, 16, 0, 0);
}

// ===========================================================================
// Phase 0: pack Wc_ih / Wc_hh transposed + k-quad-packed fp16:
//   W4T[(m*64 + kq)*256 + n] = half4{ Wc_m[n][4kq..4kq+3] }
// ===========================================================================
extern "C" __global__ void pack_kernel(const float* __restrict__ Wc_ih,
                                       const float* __restrict__ Wc_hh,
                                       uint2* __restrict__ W4T)
{
    const int n = blockIdx.x, t = threadIdx.x;
    {
        float4 v = ((const float4*)(Wc_ih + n * NN))[t];
        __half2 a = __floats2half2_rn(v.x, v.y);
        __half2 c = __floats2half2_rn(v.z, v.w);
        uint2 o; o.x = *(uint32_t*)&a; o.y = *(uint32_t*)&c;
        W4T[t * 256 + n] = o;
    }
    {
        float4 v = ((const float4*)(Wc_hh + n * NN))[t];
        __half2 a = __floats2half2_rn(v.x, v.y);
        __half2 c = __floats2half2_rn(v.z, v.w);
        uint2 o; o.x = *(uint32_t*)&a; o.y = *(uint32_t*)&c;
        W4T[(64 + t) * 256 + n] = o;
    }
}

// ===========================================================================
// Phase 1: tanh RNN. 1024 threads: (n = t&255, kq = t>>8 in 0..3).
// Weight arrays 16+64 = 80 VGPRs -> no spill at the 128-reg/16-wave budget.
// Writes A2 (B, S, N) fp16.
// ===========================================================================
extern "C" __global__ void __launch_bounds__(1024, 4)
rnn_kernel(const float* __restrict__ X, const float* __restrict__ W_ih,
           const float* __restrict__ W_hh, const float* __restrict__ b_ih,
           const float* __restrict__ b_hh, __half* __restrict__ A2)
{
    const int b = blockIdx.x, t = threadIdx.x;
    const int n = t & 255, kq = t >> 8;

    __shared__ float h_lds[NN];
    __shared__ float x_lds[NIN];
    __shared__ float part[4 * NN];

    float wih[16];
#pragma unroll
    for (int j = 0; j < 16; ++j) wih[j] = W_ih[n * NIN + kq * 16 + j];
    float whh[64];
#pragma unroll
    for (int j = 0; j < 64; ++j) whh[j] = W_hh[n * NN + kq * 64 + j];
    const float bias = b_ih[n] + b_hh[n];

    float xr = (t < NIN) ? X[b * NIN + t] : 0.f;
    if (t < NN) h_lds[t] = 0.f;
    __syncthreads();

    __half2* Ab2 = (__half2*)(A2 + (size_t)b * NSTEPS * NN);

    for (int s = 0; s < NSTEPS; ++s) {
        if (t < NIN) x_lds[t] = xr;
        __syncthreads();                               // bar1: x & h ready
        if (t < NIN && s + 1 < NSTEPS) xr = X[((s + 1) * BATCH + b) * NIN + t];

        float a0 = 0.f, a1 = 0.f;
#pragma unroll
        for (int j = 0; j < 16; ++j) a0 = fmaf(wih[j], x_lds[kq * 16 + j], a0);
#pragma unroll
        for (int j = 0; j < 64; ++j) a1 = fmaf(whh[j], h_lds[kq * 64 + j], a1);
        part[kq * NN + n] = a0 + a1;
        __syncthreads();                               // bar2: partials ready
        if (t < NN) {
            const float hn = tanhf(part[t] + part[NN + t] + part[2 * NN + t] +
                                   part[3 * NN + t] + bias);
            h_lds[t] = hn;
            const float hn1 = __shfl_down(hn, 1);
            if (!(t & 1)) Ab2[s * (NN / 2) + (t >> 1)] = __floats2half2_rn(hn, hn1);
        }
        __syncthreads();                               // bar3: h written
    }
}

// ===========================================================================
// Phase 2: 256-iteration attention loop. 512 threads, 1 block per batch row.
// A streamed in 4 chunks of 128 rows via global_load_lds (async, dbuf,
// pre-swizzled per-lane SOURCE -> linear LDS dest holds swizzled layout).
// Softmax redundantly reduced in every wave (no LDS round trip for m/l).
// Wc_ih.hp folded into chunk loop; post-loop only Wc_hh.attsum (then /l).
// ===========================================================================
#define AW2     16384                          // words per 64 KB chunk buffer
#define HP_PAD  68
#define LDS_FLOATS (2*AW2 + 272 + 272 + 2048 + 128 + 128)
#define LDS_BYTES  (LDS_FLOATS * 4)            // 142,464

extern "C" __global__ void __launch_bounds__(512, 2)
attn_kernel(const __half* __restrict__ A2, const uint2* __restrict__ W4T,
            const float* __restrict__ bc_ih, const float* __restrict__ bc_hh,
            const float* __restrict__ W_fc, const float* __restrict__ b_fc,
            float* __restrict__ out)
{
    extern __shared__ float sm[];
    uint32_t* aw      = (uint32_t*)sm;          // 2 x 16384 words
    float*    hp_lds  = sm + 2 * AW2;           // 4*68
    float*    att_lds = hp_lds + 272;           // 4*68
    float*    attp    = att_lds + 272;          // 8*256
    float*    pre_lds = attp + 2048;            // 128
    float*    e_lds   = pre_lds + 128;          // 128

    const int b    = blockIdx.x;
    const int t    = threadIdx.x;
    const int lane = t & 63;
    const int w    = t >> 6;

    const int pe = t & 7, pr = t >> 3;          // pre-dot: 8 lanes/row
    const int un = t & 255, um = t >> 8;        // Wc matvec split
    const float bcs = (t < 256) ? (bc_ih[un] + bc_hh[un]) : 0.f;

    if (t < 256) hp_lds[(t >> 6) * HP_PAD + (t & 63)] = 0.f;

    // per-lane pre-swizzled source byte offsets (8 slots per wave)
    const char* Abyte = (const char*)(A2 + (size_t)b * NSTEPS * NN);
    int soff[8];
#pragma unroll
    for (int i = 0; i < 8; ++i) {
        const int row = 16 * w + 2 * i + (lane >> 5);
        soff[i] = row * 512 + (((lane & 31) ^ (row & 7)) << 4);
    }

    // prologue: stage chunk 0 -> buffer 0
#pragma unroll
    for (int i = 0; i < 8; ++i)
        gll16(Abyte + soff[i], (char*)aw + (w * 8 + i) * 1024);
    __syncthreads();

    for (int it = 0; it < NN; ++it) {
        // hp col-slice (32 floats) for pre-dot
        float hpr[32];
        {
            const float* hb = hp_lds + (pe >> 1) * HP_PAD + (pe & 1) * 32;
#pragma unroll
            for (int j = 0; j < 8; ++j) {
                float4 v = *(const float4*)&hb[4 * j];
                hpr[4*j] = v.x; hpr[4*j+1] = v.y; hpr[4*j+2] = v.z; hpr[4*j+3] = v.w;
            }
        }

        float m = -INFINITY, l = 0.f, acc_ih = 0.f;
        float att4[4] = {0.f, 0.f, 0.f, 0.f};

        for (int c = 0; c < 4; ++c) {
            const uint32_t* ab = aw + (c & 1) * AW2;

            // async-issue next chunk into other buffer (flies across compute)
            {
                const char* src = Abyte + (((c + 1) & 3) << 16);
                char* dst = (char*)(aw + (~c & 1) * AW2);
#pragma unroll
                for (int i = 0; i < 8; ++i)
                    gll16(src + soff[i], dst + (w * 8 + i) * 1024);
            }

            // ---- pre[r] = <A_row r, hp>, 8 lanes/row, 2 row passes
#pragma unroll
            for (int pass = 0; pass < 2; ++pass) {
                const int r = pass * 64 + pr;
                const uint32_t* arow = ab + r * 128;
                const int sw = (r & 7) << 2;
                float acc = 0.f;
#pragma unroll
                for (int jj = 0; jj < 4; ++jj) {
                    uint4 wv = *(const uint4*)&arow[(pe * 16 + 4 * jj) ^ sw];
                    float2 f0 = __half22float2(*(__half2*)&wv.x);
                    float2 f1 = __half22float2(*(__half2*)&wv.y);
                    float2 f2 = __half22float2(*(__half2*)&wv.z);
                    float2 f3 = __half22float2(*(__half2*)&wv.w);
                    acc = fmaf(f0.x, hpr[8*jj+0], acc);
                    acc = fmaf(f0.y, hpr[8*jj+1], acc);
                    acc = fmaf(f1.x, hpr[8*jj+2], acc);
                    acc = fmaf(f1.y, hpr[8*jj+3], acc);
                    acc = fmaf(f2.x, hpr[8*jj+4], acc);
                    acc = fmaf(f2.y, hpr[8*jj+5], acc);
                    acc = fmaf(f3.x, hpr[8*jj+6], acc);
                    acc = fmaf(f3.y, hpr[8*jj+7], acc);
                }
                acc += __shfl_xor(acc, 1);
                acc += __shfl_xor(acc, 2);
                acc += __shfl_xor(acc, 4);
                if (pe == 0) pre_lds[r] = acc;
            }
            __syncthreads();                               // bar1

            // ---- online softmax, redundantly in every wave (shuffles only)
            {
                const float p0 = pre_lds[lane], p1 = pre_lds[64 + lane];
                float v = fmaxf(p0, p1);
#pragma unroll
                for (int o = 32; o > 0; o >>= 1) v = fmaxf(v, __shfl_xor(v, o));
                const float newm = fmaxf(m, v);
                const float rs   = expf(m - newm);         // 0 on first chunk
                const float e0 = expf(p0 - newm), e1 = expf(p1 - newm);
                float sv = e0 + e1;
#pragma unroll
                for (int o = 32; o > 0; o >>= 1) sv += __shfl_xor(sv, o);
                l = l * rs + sv;
                m = newm;
                if (w == 0) { e_lds[lane] = e0; e_lds[64 + lane] = e1; }
#pragma unroll
                for (int j = 0; j < 4; ++j) att4[j] *= rs;
            }
            __syncthreads();                               // bar2

            // ---- att accumulate: wave w -> rows w*16..+15, cols 4*lane..+3
            {
#pragma unroll
                for (int i = 0; i < 16; ++i) {
                    const int r = w * 16 + i;
                    const float e = e_lds[r];
                    uint2 wv = *(const uint2*)&ab[r * 128 + ((2 * lane) ^ ((r & 7) << 2))];
                    float2 f0 = __half22float2(*(__half2*)&wv.x);
                    float2 f1 = __half22float2(*(__half2*)&wv.y);
                    att4[0] = fmaf(e, f0.x, att4[0]);
                    att4[1] = fmaf(e, f0.y, att4[1]);
                    att4[2] = fmaf(e, f1.x, att4[2]);
                    att4[3] = fmaf(e, f1.y, att4[3]);
                }
            }

            // ---- folded Wc_ih . hp partial (8 k-quads per chunk)
            {
#pragma unroll
                for (int j = 0; j < 8; ++j) {
                    const int kq = um * 32 + c * 8 + j;
                    uint2 ww = W4T[kq * 256 + un];
                    float4 v = *(const float4*)&hp_lds[(kq >> 4) * HP_PAD + ((kq << 2) & 63)];
                    float2 f0 = __half22float2(*(__half2*)&ww.x);
                    float2 f1 = __half22float2(*(__half2*)&ww.y);
                    acc_ih = fmaf(f0.x, v.x, acc_ih);
                    acc_ih = fmaf(f0.y, v.y, acc_ih);
                    acc_ih = fmaf(f1.x, v.z, acc_ih);
                    acc_ih = fmaf(f1.y, v.w, acc_ih);
                }
            }
            __syncthreads();                               // bar3 (buffer handoff)
        }

        // ---- combine att shards (unnormalized)
        *(float4*)&attp[w * 256 + 4 * lane] =
            make_float4(att4[0], att4[1], att4[2], att4[3]);
        __syncthreads();
        if (t < 256) {
            float s = 0.f;
#pragma unroll
            for (int sh = 0; sh < 8; ++sh) s += attp[sh * 256 + t];
            att_lds[(t >> 6) * HP_PAD + (t & 63)] = s;
        }
        __syncthreads();

        // ---- Wc_hh . attsum (k-half um), then /l
        {
            float acc_hh = 0.f;
#pragma unroll
            for (int j = 0; j < 32; ++j) {
                const int kq = um * 32 + j;
                uint2 ww = W4T[(64 + kq) * 256 + un];
                float4 v = *(const float4*)&att_lds[(kq >> 4) * HP_PAD + ((kq << 2) & 63)];
                float2 f0 = __half22float2(*(__half2*)&ww.x);
                float2 f1 = __half22float2(*(__half2*)&ww.y);
                acc_hh = fmaf(f0.x, v.x, acc_hh);
                acc_hh = fmaf(f0.y, v.y, acc_hh);
                acc_hh = fmaf(f1.x, v.z, acc_hh);
                acc_hh = fmaf(f1.y, v.w, acc_hh);
            }
            attp[um * 256 + un] = acc_ih + acc_hh * (1.f / l);
        }
        __syncthreads();
        if (t < 256) {
            const float hn = tanhf(attp[t] + attp[256 + t] + bcs);
            hp_lds[(t >> 6) * HP_PAD + (t & 63)] = hn;
        }
        __syncthreads();
    }

    // ---- final FC
    float v = (t < 256) ? hp_lds[(t >> 6) * HP_PAD + (t & 63)] * W_fc[un] : 0.f;
#pragma unroll
    for (int o = 32; o > 0; o >>= 1) v += __shfl_xor(v, o);
    if (lane == 0) attp[w] = v;
    __syncthreads();
    if (t == 0) {
        float s = b_fc[0];
#pragma unroll
        for (int q = 0; q < 8; ++q) s += attp[q];
        out[b] = s;
    }
}

// ===========================================================================
extern "C" void kernel_launch(void* const* d_in, const int* in_sizes, int n_in,
                              void* d_out, int out_size, void* d_ws, size_t ws_size,
                              hipStream_t stream) {
    const float* X     = (const float*)d_in[0];
    const float* W_ih  = (const float*)d_in[1];
    const float* W_hh  = (const float*)d_in[2];
    const float* b_ih  = (const float*)d_in[3];
    const float* b_hh  = (const float*)d_in[4];
    const float* Wc_ih = (const float*)d_in[5];
    const float* Wc_hh = (const float*)d_in[6];
    const float* bc_ih = (const float*)d_in[7];
    const float* bc_hh = (const float*)d_in[8];
    const float* W_fc  = (const float*)d_in[9];
    const float* b_fc  = (const float*)d_in[10];
    float* out = (float*)d_out;

    __half* A2  = (__half*)d_ws;                                    // 64 MiB
    uint2*  W4T = (uint2*)((char*)d_ws + (size_t)64 * 1024 * 1024); // 256 KiB

    hipFuncSetAttribute((const void*)attn_kernel,
                        hipFuncAttributeMaxDynamicSharedMemorySize, LDS_BYTES);

    pack_kernel<<<256, 64, 0, stream>>>(Wc_ih, Wc_hh, W4T);
    rnn_kernel<<<BATCH, 1024, 0, stream>>>(X, W_ih, W_hh, b_ih, b_hh, A2);
    attn_kernel<<<BATCH, 512, LDS_BYTES, stream>>>(A2, W4T, bc_ih, bc_hh,
                                                   W_fc, b_fc, out);
}